// Round 1
// baseline (558.525 us; speedup 1.0000x reference)
//
#include <hip/hip_runtime.h>
#include <hip/hip_bf16.h>
#include <stdint.h>

#define Bdim 32
#define Cdim 512
#define Ndim 4096
#define Kdim 32

// ws layout:
//   [0, 8 MiB)        : w as bf16, [B][N][K]
//   +8 MiB            : c2[32] float
//   +8 MiB + 256      : wsum[B][K] float (zeroed by k0 each call)
static constexpr size_t WS_W_BYTES   = (size_t)Bdim * Ndim * Kdim * 2;  // 8388608
static constexpr size_t WS_C2_OFF    = WS_W_BYTES;
static constexpr size_t WS_WSUM_OFF  = WS_W_BYTES + 256;

// ---------------------------------------------------------------------------
// K0: compute c2[k] = sum_c cw[k][c]^2 and zero wsum. One block, 256 threads.
// ---------------------------------------------------------------------------
__global__ __launch_bounds__(256) void k0_init(const float* __restrict__ cw,
                                               float* __restrict__ c2,
                                               float* __restrict__ wsum) {
    __shared__ float part[8][32];
    int t = threadIdx.x;
    int k = t & 31, g = t >> 5;
    float s = 0.f;
    int c0 = g * 64;
    for (int c = c0; c < c0 + 64; ++c) {
        float v = cw[k * Cdim + c];
        s += v * v;
    }
    part[g][k] = s;
    __syncthreads();
    if (t < 32) {
        float tot = 0.f;
        #pragma unroll
        for (int gg = 0; gg < 8; ++gg) tot += part[gg][t];
        c2[t] = tot;
    }
    for (int i = t; i < Bdim * Kdim; i += 256) wsum[i] = 0.f;
}

// ---------------------------------------------------------------------------
// K1: per-pixel softmax weights.
// grid = 512 blocks x 256 threads; thread <-> (b, n). x reads coalesced
// (lane index = n). Codewords staged fully in LDS as [c][k] (64 KB) so the
// inner loop reads are lane-uniform float4 broadcasts (conflict-free).
// Output: w[b][n][k] in bf16 to ws; wsum accumulated via wave-butterfly +
// one atomicAdd per k per wave.
// ---------------------------------------------------------------------------
__global__ __launch_bounds__(256) void k1_weights(const float* __restrict__ x,
                                                  const float* __restrict__ cw,
                                                  const float* __restrict__ scale,
                                                  const float* __restrict__ c2,
                                                  float* __restrict__ wsum,
                                                  unsigned short* __restrict__ wout) {
    __shared__ float cw_s[Cdim][Kdim];  // 64 KB, [c][k]
    int t = threadIdx.x;

    // stage codewords: global layout [k][c] -> LDS [c][k]; global coalesced.
    #pragma unroll 4
    for (int i = 0; i < 64; ++i) {
        int flat = i * 256 + t;          // = k*512 + c
        int k = flat >> 9;
        int c = flat & 511;
        cw_s[c][k] = cw[flat];
    }
    __syncthreads();

    int gid = blockIdx.x * 256 + t;      // [0, B*N)
    int b = gid >> 12;
    int n = gid & 4095;
    const float* xp = x + (size_t)b * Cdim * Ndim + n;

    float acc[Kdim];
    #pragma unroll
    for (int k = 0; k < Kdim; ++k) acc[k] = 0.f;
    float x2 = 0.f;

    #pragma unroll 4
    for (int c = 0; c < Cdim; ++c) {
        float xv = xp[(size_t)c * Ndim];
        x2 += xv * xv;
        const float4* row = (const float4*)(&cw_s[c][0]);
        #pragma unroll
        for (int j = 0; j < 8; ++j) {
            float4 q = row[j];
            acc[4 * j + 0] += xv * q.x;
            acc[4 * j + 1] += xv * q.y;
            acc[4 * j + 2] += xv * q.z;
            acc[4 * j + 3] += xv * q.w;
        }
    }

    // dist + softmax over k (all in-thread)
    float w[Kdim];
    float m = -3.4e38f;
    #pragma unroll
    for (int k = 0; k < Kdim; ++k) {
        float d = scale[k] * (x2 - 2.f * acc[k] + c2[k]);
        w[k] = d;
        m = fmaxf(m, d);
    }
    float s = 0.f;
    #pragma unroll
    for (int k = 0; k < Kdim; ++k) {
        float e = __expf(w[k] - m);
        w[k] = e;
        s += e;
    }
    float inv = 1.f / s;
    #pragma unroll
    for (int k = 0; k < Kdim; ++k) w[k] *= inv;

    // wsum: butterfly-reduce each k over the 64-lane wave; lane k keeps sum k.
    int lane = t & 63;
    float red = 0.f;
    #pragma unroll
    for (int k = 0; k < Kdim; ++k) {
        float v = w[k];
        v += __shfl_xor(v, 32);
        v += __shfl_xor(v, 16);
        v += __shfl_xor(v, 8);
        v += __shfl_xor(v, 4);
        v += __shfl_xor(v, 2);
        v += __shfl_xor(v, 1);
        if (lane == k) red = v;
    }
    if (lane < 32) atomicAdd(&wsum[b * Kdim + lane], red);

    // store w as bf16 (RNE), 64 B per thread via 4x uint4
    union {
        unsigned short us[32];
        uint4 v4[4];
    } uw;
    #pragma unroll
    for (int k = 0; k < Kdim; ++k) {
        unsigned int ub = __float_as_uint(w[k]);
        ub += 0x7fffu + ((ub >> 16) & 1u);
        uw.us[k] = (unsigned short)(ub >> 16);
    }
    uint4* wp = (uint4*)(wout + (size_t)gid * Kdim);
    #pragma unroll
    for (int q = 0; q < 4; ++q) wp[q] = uw.v4[q];
}

// ---------------------------------------------------------------------------
// K2: out[b][k][c] = sum_n w[b][n][k] * x[b][c][n] - wsum[b][k]*cw[k][c].
// grid = 256 blocks (b x 8 c-chunks of 64) x 512 threads.
// thread: c' = t&63, kq = t>>6 (4 k's each). Sums over all 4096 n in chunks
// of 128 staged through LDS. x_s row-padded to 129 (2-way-free banks on the
// compute read); w_s padded to 36 floats (b128-aligned, lane-uniform reads).
// ---------------------------------------------------------------------------
__global__ __launch_bounds__(512) void k2_out(const float* __restrict__ x,
                                              const float* __restrict__ cw,
                                              const float* __restrict__ wsum,
                                              const unsigned short* __restrict__ w,
                                              float* __restrict__ out) {
    __shared__ float x_s[64][129];   // 33024 B
    __shared__ float w_s[128][36];   // 18432 B
    int t = threadIdx.x;
    int b = blockIdx.x >> 3;
    int c0 = (blockIdx.x & 7) * 64;
    int cp = t & 63;
    int kq = t >> 6;                 // wave-uniform (512 threads)

    float acc0 = 0.f, acc1 = 0.f, acc2 = 0.f, acc3 = 0.f;
    const float* xb = x + (size_t)b * Cdim * Ndim;
    const unsigned int* wb = (const unsigned int*)(w + (size_t)b * Ndim * Kdim);

    for (int n1 = 0; n1 < Ndim; n1 += 128) {
        __syncthreads();  // previous chunk fully consumed before overwrite
        // stage x: rows c0..c0+63, cols n1..n1+127 (8192 floats, 16/thread)
        #pragma unroll 4
        for (int i = 0; i < 16; ++i) {
            int flat = i * 512 + t;
            int cc = flat >> 7;
            int fi = flat & 127;
            x_s[cc][fi] = xb[(size_t)(c0 + cc) * Ndim + n1 + fi];
        }
        // stage w: [128 n][32 k] from packed bf16 pairs (2048 uints, 4/thread)
        #pragma unroll
        for (int i = 0; i < 4; ++i) {
            int flat = i * 512 + t;       // 0..2047
            int kp = flat & 15;
            int nn = flat >> 4;           // 0..127
            unsigned int u = wb[(size_t)(n1 + nn) * 16 + kp];
            w_s[nn][2 * kp + 0] = __uint_as_float(u << 16);
            w_s[nn][2 * kp + 1] = __uint_as_float(u & 0xffff0000u);
        }
        __syncthreads();
        #pragma unroll 4
        for (int nn = 0; nn < 128; ++nn) {
            float xv = x_s[cp][nn];
            float4 q = *(const float4*)&w_s[nn][4 * kq];
            acc0 += xv * q.x;
            acc1 += xv * q.y;
            acc2 += xv * q.z;
            acc3 += xv * q.w;
        }
    }

    int k = kq * 4;
    int c = c0 + cp;
    size_t obase = ((size_t)b * Kdim) * Cdim;
    float s0 = wsum[b * Kdim + k + 0];
    float s1 = wsum[b * Kdim + k + 1];
    float s2 = wsum[b * Kdim + k + 2];
    float s3 = wsum[b * Kdim + k + 3];
    out[obase + (size_t)(k + 0) * Cdim + c] = acc0 - s0 * cw[(k + 0) * Cdim + c];
    out[obase + (size_t)(k + 1) * Cdim + c] = acc1 - s1 * cw[(k + 1) * Cdim + c];
    out[obase + (size_t)(k + 2) * Cdim + c] = acc2 - s2 * cw[(k + 2) * Cdim + c];
    out[obase + (size_t)(k + 3) * Cdim + c] = acc3 - s3 * cw[(k + 3) * Cdim + c];
}

// ---------------------------------------------------------------------------
extern "C" void kernel_launch(void* const* d_in, const int* in_sizes, int n_in,
                              void* d_out, int out_size, void* d_ws, size_t ws_size,
                              hipStream_t stream) {
    const float* x     = (const float*)d_in[0];   // [B][C][N]
    const float* cw    = (const float*)d_in[1];   // [K][C]
    const float* scale = (const float*)d_in[2];   // [K]
    float* out = (float*)d_out;                   // [B][K][C]

    char* wsb = (char*)d_ws;
    unsigned short* wbuf = (unsigned short*)wsb;
    float* c2   = (float*)(wsb + WS_C2_OFF);
    float* wsum = (float*)(wsb + WS_WSUM_OFF);

    k0_init<<<1, 256, 0, stream>>>(cw, c2, wsum);
    k1_weights<<<(Bdim * Ndim) / 256, 256, 0, stream>>>(x, cw, scale, c2, wsum, wbuf);
    k2_out<<<Bdim * 8, 512, 0, stream>>>(x, cw, wsum, wbuf, out);
}

// Round 3
// 420.796 us; speedup vs baseline: 1.3273x; 1.3273x over previous
//
#include <hip/hip_runtime.h>
#include <hip/hip_bf16.h>
#include <stdint.h>

#define Bdim 32
#define Cdim 512
#define Ndim 4096
#define Kdim 32
#define NCHUNK 32           // pixels per chunk
#define NCHUNKS 8           // chunks per fused block
#define PBLK 16             // fused blocks per batch image  (PBLK*NCHUNKS*NCHUNK = Ndim)

// ws layout:
//   [0, 33 554 432)            : part_out [512 blk][K][C] fp32
//   +33 554 432 (64 KiB)       : wsum_part [512 blk][K] fp32
//   +33 619 968 (128 B)        : c2[K] fp32
static constexpr size_t WS_WSUM_OFF = (size_t)512 * Kdim * Cdim * 4;   // 33554432
static constexpr size_t WS_C2_OFF   = WS_WSUM_OFF + (size_t)512 * Kdim * 4;

typedef __fp16 hf2 __attribute__((ext_vector_type(2)));      // storage / cvt_pkrtz type
typedef _Float16 ff2 __attribute__((ext_vector_type(2)));    // alt builtin arg type

static __device__ __forceinline__ float dot2f(hf2 a, hf2 b, float c) {
#if __has_builtin(__builtin_amdgcn_fdot2)
    return __builtin_amdgcn_fdot2(__builtin_bit_cast(ff2, a),
                                  __builtin_bit_cast(ff2, b), c, false);
#else
    return c + (float)a[0] * (float)b[0] + (float)a[1] * (float)b[1];
#endif
}

// ---------------------------------------------------------------------------
// K0: c2[k] = sum_c cw[k][c]^2. One block, 256 threads.
// ---------------------------------------------------------------------------
__global__ __launch_bounds__(256) void k0_c2(const float* __restrict__ cw,
                                             float* __restrict__ c2) {
    __shared__ float partl[8][32];
    int t = threadIdx.x;
    int k = t & 31, g = t >> 5;
    float s = 0.f;
    int c0 = g * 64;
    for (int c = c0; c < c0 + 64; ++c) {
        float v = cw[k * Cdim + c];
        s += v * v;
    }
    partl[g][k] = s;
    __syncthreads();
    if (t < 32) {
        float tot = 0.f;
        #pragma unroll
        for (int gg = 0; gg < 8; ++gg) tot += partl[gg][t];
        c2[t] = tot;
    }
}

// ---------------------------------------------------------------------------
// K1 fused: per block (b, p): loop over 8 chunks of 32 pixels.
//   stage x chunk -> LDS f16 (+exact fp32 x2), pass1 scores via v_dot2,
//   softmax in LDS (fp32 w), pass2 accumulate [K][C] tile in registers.
// Epilogue: write partial [K][C] + partial wsum[K] to ws.
// LDS: xh 33280 + cwh 32768 + w_s 4608 + x2_s 128 = 70784 B -> 2 blocks/CU.
// ---------------------------------------------------------------------------
__global__ __launch_bounds__(256, 2) void k1_fused(const float* __restrict__ x,
                                                   const float* __restrict__ cw,
                                                   const float* __restrict__ scale,
                                                   const float* __restrict__ c2g,
                                                   float* __restrict__ part,
                                                   float* __restrict__ wsum_part) {
    __shared__ hf2   xh[NCHUNK][260];   // [n][c-pair], stride 260 (b128-aligned)
    __shared__ hf2   cwh[Kdim][256];    // [k][c-pair]
    __shared__ float w_s[NCHUNK][36];   // [n][k] scores -> weights
    __shared__ float x2_s[NCHUNK];

    const int t   = threadIdx.x;
    const int blk = blockIdx.x;
    const int b   = blk >> 4;
    const int p   = blk & 15;

    // pass-1 ids
    const int n1 = t & 31;
    const int kq = t >> 5;          // 0..7 -> k = 4*kq..+3
    // staging ids
    const int q   = t & 7;          // n-quad (n = 4q..4q+3)
    const int cc0 = t >> 3;         // 0..31 c-pair base
    // pass-2 ids
    const int cg = t & 63;          // c-octet: c = 8cg..8cg+7
    const int kh = t >> 6;          // 0..3   : k = 8kh..8kh+7 (wave-uniform)

    float sc[4], cc2[4];
    #pragma unroll
    for (int j = 0; j < 4; ++j) {
        sc[j]  = scale[4 * kq + j];
        cc2[j] = c2g[4 * kq + j];
    }

    // ---- one-time: stage codewords to f16 LDS; zero x2_s ----
    if (t < NCHUNK) x2_s[t] = 0.f;
    #pragma unroll
    for (int i = 0; i < 16; ++i) {
        int f4 = t + 256 * i;            // float4 index over [K][C/4]
        int k  = f4 >> 7;
        int c4 = f4 & 127;
        float4 v = *(const float4*)(cw + (size_t)k * Cdim + 4 * c4);
        cwh[k][2 * c4 + 0] = __builtin_amdgcn_cvt_pkrtz(v.x, v.y);
        cwh[k][2 * c4 + 1] = __builtin_amdgcn_cvt_pkrtz(v.z, v.w);
    }

    float acc[8][8];                     // [kk][cj] output tile
    #pragma unroll
    for (int a = 0; a < 8; ++a)
        #pragma unroll
        for (int d = 0; d < 8; ++d) acc[a][d] = 0.f;
    float wsum_r = 0.f;                  // valid for t<32

    const float* xb = x + (size_t)b * Cdim * Ndim + p * (NCHUNKS * NCHUNK);
    __syncthreads();

    for (int ci = 0; ci < NCHUNKS; ++ci) {
        const int n0 = ci * NCHUNK;

        // ---------------- stage x chunk ----------------
        float x2p[4] = {0.f, 0.f, 0.f, 0.f};
        #pragma unroll
        for (int it = 0; it < 8; ++it) {
            int cc = cc0 + 32 * it;                       // c-pair 0..255
            const float* r0 = xb + (size_t)(2 * cc) * Ndim + n0 + 4 * q;
            float4 a  = *(const float4*)r0;
            float4 bb = *(const float4*)(r0 + Ndim);
            xh[4 * q + 0][cc] = __builtin_amdgcn_cvt_pkrtz(a.x, bb.x);
            xh[4 * q + 1][cc] = __builtin_amdgcn_cvt_pkrtz(a.y, bb.y);
            xh[4 * q + 2][cc] = __builtin_amdgcn_cvt_pkrtz(a.z, bb.z);
            xh[4 * q + 3][cc] = __builtin_amdgcn_cvt_pkrtz(a.w, bb.w);
            x2p[0] += a.x * a.x + bb.x * bb.x;
            x2p[1] += a.y * a.y + bb.y * bb.y;
            x2p[2] += a.z * a.z + bb.z * bb.z;
            x2p[3] += a.w * a.w + bb.w * bb.w;
        }
        // reduce x2 partials across the 8 cc-lanes of each wave, then 4 atomics
        #pragma unroll
        for (int j = 0; j < 4; ++j) {
            float v = x2p[j];
            v += __shfl_xor(v, 8);
            v += __shfl_xor(v, 16);
            v += __shfl_xor(v, 32);
            if ((t & 56) == 0) atomicAdd(&x2_s[4 * q + j], v);
        }
        __syncthreads();

        // ---------------- pass 1: scores ----------------
        {
            const int k0 = 4 * kq;
            float d0 = 0.f, d1 = 0.f, d2 = 0.f, d3 = 0.f;
            #pragma unroll 4
            for (int cp = 0; cp < 64; ++cp) {
                uint4 xu = *(const uint4*)&xh[n1][4 * cp];
                hf2 x0 = __builtin_bit_cast(hf2, xu.x);
                hf2 x1 = __builtin_bit_cast(hf2, xu.y);
                hf2 x2v = __builtin_bit_cast(hf2, xu.z);
                hf2 x3 = __builtin_bit_cast(hf2, xu.w);
                uint4 cu0 = *(const uint4*)&cwh[k0 + 0][4 * cp];
                uint4 cu1 = *(const uint4*)&cwh[k0 + 1][4 * cp];
                uint4 cu2 = *(const uint4*)&cwh[k0 + 2][4 * cp];
                uint4 cu3 = *(const uint4*)&cwh[k0 + 3][4 * cp];
                d0 = dot2f(x0, __builtin_bit_cast(hf2, cu0.x), d0);
                d0 = dot2f(x1, __builtin_bit_cast(hf2, cu0.y), d0);
                d0 = dot2f(x2v, __builtin_bit_cast(hf2, cu0.z), d0);
                d0 = dot2f(x3, __builtin_bit_cast(hf2, cu0.w), d0);
                d1 = dot2f(x0, __builtin_bit_cast(hf2, cu1.x), d1);
                d1 = dot2f(x1, __builtin_bit_cast(hf2, cu1.y), d1);
                d1 = dot2f(x2v, __builtin_bit_cast(hf2, cu1.z), d1);
                d1 = dot2f(x3, __builtin_bit_cast(hf2, cu1.w), d1);
                d2 = dot2f(x0, __builtin_bit_cast(hf2, cu2.x), d2);
                d2 = dot2f(x1, __builtin_bit_cast(hf2, cu2.y), d2);
                d2 = dot2f(x2v, __builtin_bit_cast(hf2, cu2.z), d2);
                d2 = dot2f(x3, __builtin_bit_cast(hf2, cu2.w), d2);
                d3 = dot2f(x0, __builtin_bit_cast(hf2, cu3.x), d3);
                d3 = dot2f(x1, __builtin_bit_cast(hf2, cu3.y), d3);
                d3 = dot2f(x2v, __builtin_bit_cast(hf2, cu3.z), d3);
                d3 = dot2f(x3, __builtin_bit_cast(hf2, cu3.w), d3);
            }
            float xx = x2_s[n1];
            w_s[n1][k0 + 0] = sc[0] * (xx - 2.f * d0 + cc2[0]);
            w_s[n1][k0 + 1] = sc[1] * (xx - 2.f * d1 + cc2[1]);
            w_s[n1][k0 + 2] = sc[2] * (xx - 2.f * d2 + cc2[2]);
            w_s[n1][k0 + 3] = sc[3] * (xx - 2.f * d3 + cc2[3]);
        }
        __syncthreads();

        // ---------------- softmax over k (32 threads, 1 pixel each) --------
        if (t < 32) {
            float v[32];
            float m = -3.4e38f;
            #pragma unroll
            for (int k = 0; k < 32; ++k) {
                v[k] = w_s[t][k];
                m = fmaxf(m, v[k]);
            }
            float s = 0.f;
            #pragma unroll
            for (int k = 0; k < 32; ++k) {
                v[k] = __expf(v[k] - m);
                s += v[k];
            }
            float inv = 1.f / s;
            #pragma unroll
            for (int k = 0; k < 32; ++k) w_s[t][k] = v[k] * inv;
        }
        __syncthreads();

        // ---------------- pass 2: accumulate [K][C] tile ----------------
        {
            const int k0 = 8 * kh;
            #pragma unroll 4
            for (int n = 0; n < NCHUNK; ++n) {
                uint4 xu = *(const uint4*)&xh[n][4 * cg];
                hf2 h0 = __builtin_bit_cast(hf2, xu.x);
                hf2 h1 = __builtin_bit_cast(hf2, xu.y);
                hf2 h2 = __builtin_bit_cast(hf2, xu.z);
                hf2 h3 = __builtin_bit_cast(hf2, xu.w);
                float xf[8];
                xf[0] = (float)h0[0]; xf[1] = (float)h0[1];
                xf[2] = (float)h1[0]; xf[3] = (float)h1[1];
                xf[4] = (float)h2[0]; xf[5] = (float)h2[1];
                xf[6] = (float)h3[0]; xf[7] = (float)h3[1];
                float4 wa = *(const float4*)&w_s[n][k0];
                float4 wb = *(const float4*)&w_s[n][k0 + 4];
                float wv[8] = {wa.x, wa.y, wa.z, wa.w, wb.x, wb.y, wb.z, wb.w};
                #pragma unroll
                for (int kk = 0; kk < 8; ++kk)
                    #pragma unroll
                    for (int j = 0; j < 8; ++j)
                        acc[kk][j] += wv[kk] * xf[j];
            }
        }
        // wsum partial (t<32) and zero x2_s for next chunk (t in [32,64))
        if (t < 32) {
            float s = 0.f;
            #pragma unroll 4
            for (int n = 0; n < NCHUNK; ++n) s += w_s[n][t];
            wsum_r += s;
        } else if (t < 64) {
            x2_s[t - 32] = 0.f;
        }
        __syncthreads();
    }

    // ---------------- epilogue: partials to ws ----------------
    {
        const int k0 = 8 * kh;
        float* pb = part + (size_t)blk * (Kdim * Cdim);
        #pragma unroll
        for (int kk = 0; kk < 8; ++kk) {
            float4 v0 = make_float4(acc[kk][0], acc[kk][1], acc[kk][2], acc[kk][3]);
            float4 v1 = make_float4(acc[kk][4], acc[kk][5], acc[kk][6], acc[kk][7]);
            float* op = pb + (size_t)(k0 + kk) * Cdim + 8 * cg;
            *(float4*)op = v0;
            *(float4*)(op + 4) = v1;
        }
        if (t < 32) wsum_part[blk * Kdim + t] = wsum_r;
    }
}

// ---------------------------------------------------------------------------
// K2: reduce 16 partials per (b,k) row + subtract wsum*cw.
// grid = B*K = 1024 blocks x 256 threads (2 c per thread).
// ---------------------------------------------------------------------------
__global__ __launch_bounds__(256) void k2_reduce(const float* __restrict__ part,
                                                 const float* __restrict__ wsum_part,
                                                 const float* __restrict__ cw,
                                                 float* __restrict__ out) {
    int blk = blockIdx.x;
    int b = blk >> 5, k = blk & 31;
    int t = threadIdx.x;
    float ws = 0.f;
    #pragma unroll
    for (int p = 0; p < PBLK; ++p) ws += wsum_part[(b * PBLK + p) * Kdim + k];
    int c = 2 * t;
    float sx = 0.f, sy = 0.f;
    #pragma unroll
    for (int p = 0; p < PBLK; ++p) {
        const float2 v = *(const float2*)(part + ((size_t)(b * PBLK + p) * Kdim + k) * Cdim + c);
        sx += v.x;
        sy += v.y;
    }
    float2 cv = *(const float2*)(cw + (size_t)k * Cdim + c);
    float2 o;
    o.x = sx - ws * cv.x;
    o.y = sy - ws * cv.y;
    *(float2*)(out + ((size_t)b * Kdim + k) * Cdim + c) = o;
}

// ---------------------------------------------------------------------------
extern "C" void kernel_launch(void* const* d_in, const int* in_sizes, int n_in,
                              void* d_out, int out_size, void* d_ws, size_t ws_size,
                              hipStream_t stream) {
    const float* x     = (const float*)d_in[0];   // [B][C][N]
    const float* cw    = (const float*)d_in[1];   // [K][C]
    const float* scale = (const float*)d_in[2];   // [K]
    float* out = (float*)d_out;                   // [B][K][C]

    char* wsb = (char*)d_ws;
    float* part      = (float*)wsb;
    float* wsum_part = (float*)(wsb + WS_WSUM_OFF);
    float* c2        = (float*)(wsb + WS_C2_OFF);

    k0_c2<<<1, 256, 0, stream>>>(cw, c2);
    k1_fused<<<Bdim * PBLK, 256, 0, stream>>>(x, cw, scale, c2, part, wsum_part);
    k2_reduce<<<Bdim * Kdim, 256, 0, stream>>>(part, wsum_part, cw, out);
}

// Round 4
// 384.425 us; speedup vs baseline: 1.4529x; 1.0946x over previous
//
#include <hip/hip_runtime.h>
#include <stdint.h>

#define Bdim 32
#define Cdim 512
#define Ndim 4096
#define Kdim 32
#define NPX 32          // pixels per chunk
#define NCH 16          // chunks per block (512 px)
#define PWIN 8          // px-windows per image; grid k1 = Bdim*PWIN = 256

// ws: part[256][K][C] f32 (16 MiB) | wsum_part[256][K] | c2[K]
static constexpr size_t WS_WSUM_OFF = (size_t)256 * Kdim * Cdim * 4;          // 16777216
static constexpr size_t WS_C2_OFF   = WS_WSUM_OFF + (size_t)256 * Kdim * 4;   // +32768

using bf16x8 = __attribute__((ext_vector_type(8))) short;
using f32x4  = __attribute__((ext_vector_type(4))) float;

static __device__ __forceinline__ unsigned short f2bf(float f) {
    unsigned int u = __float_as_uint(f);
    u += 0x7fffu + ((u >> 16) & 1u);
    return (unsigned short)(u >> 16);
}

// ---------------------------------------------------------------------------
// K0: c2[k] = sum_c cw[k][c]^2
// ---------------------------------------------------------------------------
__global__ __launch_bounds__(256) void k0_c2(const float* __restrict__ cw,
                                             float* __restrict__ c2) {
    __shared__ float partl[8][32];
    int t = threadIdx.x;
    int k = t & 31, g = t >> 5;
    float s = 0.f;
    int c0 = g * 64;
    for (int c = c0; c < c0 + 64; ++c) {
        float v = cw[k * Cdim + c];
        s += v * v;
    }
    partl[g][k] = s;
    __syncthreads();
    if (t < 32) {
        float tot = 0.f;
        #pragma unroll
        for (int gg = 0; gg < 8; ++gg) tot += partl[gg][t];
        c2[t] = tot;
    }
}

// ---------------------------------------------------------------------------
// K1: fully fused, MFMA both passes. 256 blocks x 256 threads (1 block/CU).
// ---------------------------------------------------------------------------
__global__ __launch_bounds__(256) void k1_fused(const float* __restrict__ x,
                                                const float* __restrict__ cw,
                                                const float* __restrict__ scale,
                                                const float* __restrict__ c2g,
                                                float* __restrict__ part,
                                                float* __restrict__ wsum_part) {
    __shared__ unsigned short cw_s[Kdim][520];   // [k][c] bf16, pass1-B
    __shared__ unsigned short x_n[NPX][520];     // [px][c] bf16, pass1-A
    __shared__ unsigned short x_t[Cdim][40];     // [c][px] bf16, pass2-B
    __shared__ float          S_s[NPX][36];      // raw dots
    __shared__ unsigned short w_t[Kdim][40];     // [k][px] bf16, pass2-A
    __shared__ float          x2_s[NPX];
    __shared__ float          wsum_s[Kdim];

    const int t    = threadIdx.x;
    const int blk  = blockIdx.x;
    const int b    = blk >> 3;
    const int pw   = blk & 7;
    const int lane = t & 63;
    const int lr   = lane & 15;
    const int lq   = lane >> 4;
    const int wv   = t >> 6;       // wave 0..3
    const int q    = t & 7;        // staging px-quad / softmax k-quad
    const int px   = t >> 3;       // softmax pixel 0..31 (= staging c-group)

    if (t < 32) { x2_s[t] = 0.f; wsum_s[t] = 0.f; }

    // one-time: cw -> bf16 LDS
    #pragma unroll
    for (int i = 0; i < 16; ++i) {
        int f4 = t + 256 * i;              // over [32 k][128 c4]
        int k  = f4 >> 7;
        int c4 = (f4 & 127) * 4;
        float4 v = *(const float4*)(cw + (size_t)k * Cdim + c4);
        ushort4 u;
        u.x = f2bf(v.x); u.y = f2bf(v.y); u.z = f2bf(v.z); u.w = f2bf(v.w);
        *(ushort4*)&cw_s[k][c4] = u;
    }

    const float4 sc4 = *(const float4*)(scale + 4 * q);
    const float4 c24 = *(const float4*)(c2g + 4 * q);

    const float* xb = x + (size_t)b * Cdim * Ndim;

    // prefetch chunk 0: thread covers c rows {2*px + 64i, +1} at px-quad 4q
    float4 pa[8], pb[8];
    {
        int n0 = pw * 512;
        #pragma unroll
        for (int i = 0; i < 8; ++i) {
            int c = 2 * px + 64 * i;
            pa[i] = *(const float4*)(xb + (size_t)c * Ndim + n0 + 4 * q);
            pb[i] = *(const float4*)(xb + (size_t)(c + 1) * Ndim + n0 + 4 * q);
        }
    }

    f32x4 acc[2][8];
    #pragma unroll
    for (int kt = 0; kt < 2; ++kt)
        #pragma unroll
        for (int ct = 0; ct < 8; ++ct) acc[kt][ct] = (f32x4){0.f, 0.f, 0.f, 0.f};
    float wsum_r[4] = {0.f, 0.f, 0.f, 0.f};

    __syncthreads();   // covers zero-init + cw staging

    for (int ci = 0; ci < NCH; ++ci) {
        // ---------------- stage x from prefetch regs ----------------
        float x2p[4] = {0.f, 0.f, 0.f, 0.f};
        #pragma unroll
        for (int i = 0; i < 8; ++i) {
            int c = 2 * px + 64 * i;
            float4 a = pa[i], bb = pb[i];
            ushort4 ua, ub;
            ua.x = f2bf(a.x);  ua.y = f2bf(a.y);  ua.z = f2bf(a.z);  ua.w = f2bf(a.w);
            ub.x = f2bf(bb.x); ub.y = f2bf(bb.y); ub.z = f2bf(bb.z); ub.w = f2bf(bb.w);
            *(ushort4*)&x_t[c][4 * q]     = ua;
            *(ushort4*)&x_t[c + 1][4 * q] = ub;
            ushort2 p0; p0.x = ua.x; p0.y = ub.x; *(ushort2*)&x_n[4 * q + 0][c] = p0;
            ushort2 p1; p1.x = ua.y; p1.y = ub.y; *(ushort2*)&x_n[4 * q + 1][c] = p1;
            ushort2 p2; p2.x = ua.z; p2.y = ub.z; *(ushort2*)&x_n[4 * q + 2][c] = p2;
            ushort2 p3; p3.x = ua.w; p3.y = ub.w; *(ushort2*)&x_n[4 * q + 3][c] = p3;
            x2p[0] += a.x * a.x + bb.x * bb.x;
            x2p[1] += a.y * a.y + bb.y * bb.y;
            x2p[2] += a.z * a.z + bb.z * bb.z;
            x2p[3] += a.w * a.w + bb.w * bb.w;
        }
        #pragma unroll
        for (int j = 0; j < 4; ++j) {
            float v = x2p[j];
            v += __shfl_xor(v, 8);
            v += __shfl_xor(v, 16);
            v += __shfl_xor(v, 32);
            if (lane < 8) atomicAdd(&x2_s[4 * q + j], v);
        }
        // prefetch next chunk (overlaps pass1/softmax/pass2)
        if (ci + 1 < NCH) {
            int nn = pw * 512 + (ci + 1) * 32;
            #pragma unroll
            for (int i = 0; i < 8; ++i) {
                int c = 2 * px + 64 * i;
                pa[i] = *(const float4*)(xb + (size_t)c * Ndim + nn + 4 * q);
                pb[i] = *(const float4*)(xb + (size_t)(c + 1) * Ndim + nn + 4 * q);
            }
        }
        __syncthreads();

        // ---------------- pass 1: dots via MFMA ----------------
        {
            const int pt = wv & 1, kt2 = wv >> 1;
            f32x4 d = (f32x4){0.f, 0.f, 0.f, 0.f};
            #pragma unroll
            for (int s = 0; s < 16; ++s) {
                bf16x8 av = *(const bf16x8*)&x_n[16 * pt + lr][32 * s + 8 * lq];
                bf16x8 bv = *(const bf16x8*)&cw_s[16 * kt2 + lr][32 * s + 8 * lq];
                d = __builtin_amdgcn_mfma_f32_16x16x32_bf16(av, bv, d, 0, 0, 0);
            }
            #pragma unroll
            for (int r = 0; r < 4; ++r)
                S_s[16 * pt + 4 * lq + r][16 * kt2 + lr] = d[r];
        }
        __syncthreads();

        // ---------------- softmax (thread: px = t>>3, k-quad q) ----------------
        {
            float4 dv = *(const float4*)&S_s[px][4 * q];
            float xx = x2_s[px];
            float d0 = sc4.x * (xx - 2.f * dv.x + c24.x);
            float d1 = sc4.y * (xx - 2.f * dv.y + c24.y);
            float d2 = sc4.z * (xx - 2.f * dv.z + c24.z);
            float d3 = sc4.w * (xx - 2.f * dv.w + c24.w);
            float m = fmaxf(fmaxf(d0, d1), fmaxf(d2, d3));
            m = fmaxf(m, __shfl_xor(m, 1));
            m = fmaxf(m, __shfl_xor(m, 2));
            m = fmaxf(m, __shfl_xor(m, 4));
            float e0 = __expf(d0 - m), e1 = __expf(d1 - m);
            float e2 = __expf(d2 - m), e3 = __expf(d3 - m);
            float ss = e0 + e1 + e2 + e3;
            ss += __shfl_xor(ss, 1);
            ss += __shfl_xor(ss, 2);
            ss += __shfl_xor(ss, 4);
            float inv = 1.f / ss;
            float w0 = e0 * inv, w1 = e1 * inv, w2 = e2 * inv, w3 = e3 * inv;
            wsum_r[0] += w0; wsum_r[1] += w1; wsum_r[2] += w2; wsum_r[3] += w3;
            w_t[4 * q + 0][px] = f2bf(w0);
            w_t[4 * q + 1][px] = f2bf(w1);
            w_t[4 * q + 2][px] = f2bf(w2);
            w_t[4 * q + 3][px] = f2bf(w3);
        }
        __syncthreads();

        // ---------------- pass 2: out-tile MFMA, wave owns 128 c ----------------
        {
            const int c0w = 128 * wv;
            bf16x8 a0 = *(const bf16x8*)&w_t[lr][8 * lq];
            bf16x8 a1 = *(const bf16x8*)&w_t[16 + lr][8 * lq];
            if (t < 32) x2_s[t] = 0.f;   // re-arm for next chunk
            #pragma unroll
            for (int ct = 0; ct < 8; ++ct) {
                bf16x8 bv = *(const bf16x8*)&x_t[c0w + 16 * ct + lr][8 * lq];
                acc[0][ct] = __builtin_amdgcn_mfma_f32_16x16x32_bf16(a0, bv, acc[0][ct], 0, 0, 0);
                acc[1][ct] = __builtin_amdgcn_mfma_f32_16x16x32_bf16(a1, bv, acc[1][ct], 0, 0, 0);
            }
        }
        __syncthreads();   // x_t/x_n/w_t reusable next chunk
    }

    // ---------------- epilogue ----------------
    #pragma unroll
    for (int j = 0; j < 4; ++j) {
        float v = wsum_r[j];
        v += __shfl_xor(v, 8);
        v += __shfl_xor(v, 16);
        v += __shfl_xor(v, 32);
        if (lane < 8) atomicAdd(&wsum_s[4 * q + j], v);
    }
    {
        const int c0w = 128 * wv;
        float* pbuf = part + (size_t)blk * (Kdim * Cdim);
        #pragma unroll
        for (int kt = 0; kt < 2; ++kt)
            #pragma unroll
            for (int ct = 0; ct < 8; ++ct)
                #pragma unroll
                for (int r = 0; r < 4; ++r)
                    pbuf[(size_t)(16 * kt + 4 * lq + r) * Cdim + c0w + 16 * ct + lr] =
                        acc[kt][ct][r];
    }
    __syncthreads();
    if (t < 32) wsum_part[blk * Kdim + t] = wsum_s[t];
}

// ---------------------------------------------------------------------------
// K2: reduce 8 partials per (b,k) + subtract wsum*cw.
// ---------------------------------------------------------------------------
__global__ __launch_bounds__(256) void k2_reduce(const float* __restrict__ part,
                                                 const float* __restrict__ wsum_part,
                                                 const float* __restrict__ cw,
                                                 float* __restrict__ out) {
    int blk = blockIdx.x;
    int b = blk >> 5, k = blk & 31;
    int t = threadIdx.x;
    float ws = 0.f;
    #pragma unroll
    for (int p = 0; p < PWIN; ++p) ws += wsum_part[(b * PWIN + p) * Kdim + k];
    int c = 2 * t;
    float sx = 0.f, sy = 0.f;
    #pragma unroll
    for (int p = 0; p < PWIN; ++p) {
        const float2 v = *(const float2*)(part + ((size_t)(b * PWIN + p) * Kdim + k) * Cdim + c);
        sx += v.x;
        sy += v.y;
    }
    float2 cv = *(const float2*)(cw + (size_t)k * Cdim + c);
    float2 o;
    o.x = sx - ws * cv.x;
    o.y = sy - ws * cv.y;
    *(float2*)(out + ((size_t)b * Kdim + k) * Cdim + c) = o;
}

// ---------------------------------------------------------------------------
extern "C" void kernel_launch(void* const* d_in, const int* in_sizes, int n_in,
                              void* d_out, int out_size, void* d_ws, size_t ws_size,
                              hipStream_t stream) {
    const float* x     = (const float*)d_in[0];   // [B][C][N]
    const float* cw    = (const float*)d_in[1];   // [K][C]
    const float* scale = (const float*)d_in[2];   // [K]
    float* out = (float*)d_out;                   // [B][K][C]

    char* wsb = (char*)d_ws;
    float* part      = (float*)wsb;
    float* wsum_part = (float*)(wsb + WS_WSUM_OFF);
    float* c2        = (float*)(wsb + WS_C2_OFF);

    k0_c2<<<1, 256, 0, stream>>>(cw, c2);
    k1_fused<<<Bdim * PWIN, 256, 0, stream>>>(x, cw, scale, c2, part, wsum_part);
    k2_reduce<<<Bdim * Kdim, 256, 0, stream>>>(part, wsum_part, cw, out);
}

// Round 5
// 381.557 us; speedup vs baseline: 1.4638x; 1.0075x over previous
//
#include <hip/hip_runtime.h>
#include <stdint.h>

#define Bdim 32
#define Cdim 512
#define Ndim 4096
#define Kdim 32
#define NPX 32          // pixels per chunk
#define NCH 16          // chunks per block (512 px window)
#define PWIN 8          // px-windows per image; grid k1 = Bdim*PWIN = 256

// ws: part[256][K][C] f32 (16 MiB) | wsum_part[256][K] | c2[K]
static constexpr size_t WS_WSUM_OFF = (size_t)256 * Kdim * Cdim * 4;          // 16777216
static constexpr size_t WS_C2_OFF   = WS_WSUM_OFF + (size_t)256 * Kdim * 4;   // +32768

using bf16x8 = __attribute__((ext_vector_type(8))) short;
using f32x4  = __attribute__((ext_vector_type(4))) float;

static __device__ __forceinline__ unsigned short f2bf(float f) {
    unsigned int u = __float_as_uint(f);
    u += 0x7fffu + ((u >> 16) & 1u);
    return (unsigned short)(u >> 16);
}

// ---------------------------------------------------------------------------
// K0: c2[k] = sum_c cw[k][c]^2
// ---------------------------------------------------------------------------
__global__ __launch_bounds__(256) void k0_c2(const float* __restrict__ cw,
                                             float* __restrict__ c2) {
    __shared__ float partl[8][32];
    int t = threadIdx.x;
    int k = t & 31, g = t >> 5;
    float s = 0.f;
    int c0 = g * 64;
    for (int c = c0; c < c0 + 64; ++c) {
        float v = cw[k * Cdim + c];
        s += v * v;
    }
    partl[g][k] = s;
    __syncthreads();
    if (t < 32) {
        float tot = 0.f;
        #pragma unroll
        for (int gg = 0; gg < 8; ++gg) tot += partl[gg][t];
        c2[t] = tot;
    }
}

// ---------------------------------------------------------------------------
// K1: fused, MFMA both passes. 256 blocks x 512 threads (1 blk/CU, 2 w/SIMD).
// ---------------------------------------------------------------------------
__global__ __launch_bounds__(512, 2) void k1_fused(const float* __restrict__ x,
                                                   const float* __restrict__ cw,
                                                   const float* __restrict__ scale,
                                                   const float* __restrict__ c2g,
                                                   float* __restrict__ part,
                                                   float* __restrict__ wsum_part) {
    __shared__ unsigned short cw_s[Kdim][520];    // [k][c] bf16, pass1-B
    __shared__ unsigned short x_n[NPX][520];      // [px][c] bf16, pass1-A
    __shared__ unsigned short x_t[Cdim][40];      // [c][px] bf16, pass2-B
    __shared__ float          S_s[2][NPX][36];    // raw dots, c-halves
    __shared__ unsigned short w_t[Kdim][40];      // [k][px] bf16, pass2-A
    __shared__ float          x2_w[8][NPX];       // per-wave x2 partials
    __shared__ float          wsum_w[4][Kdim];    // per-wave wsum partials

    const int t    = threadIdx.x;
    const int blk  = blockIdx.x;
    const int b    = blk >> 3;
    const int pw   = blk & 7;
    const int lane = t & 63;
    const int lr   = lane & 15;
    const int lq   = lane >> 4;
    const int wv   = t >> 6;        // wave 0..7
    // staging ids: px-pair pp, c-row-group crg
    const int pp   = t & 15;        // px = 2pp, 2pp+1
    const int crg  = t >> 4;        // 0..31 -> c = 2crg + 64i (pairs c,c+1)
    // softmax ids (t < 256)
    const int q    = t & 7;         // k-quad
    const int px   = t >> 3;        // 0..31
    // pass-1 wave roles
    const int pt   = wv & 1;        // px half
    const int kt2  = (wv >> 1) & 1; // k half
    const int ch   = wv >> 2;       // c half

    // one-time: cw -> bf16 LDS (512 threads, 8 float4 each)
    #pragma unroll
    for (int i = 0; i < 8; ++i) {
        int f4 = t + 512 * i;              // over [32 k][128 c4]
        int k  = f4 >> 7;
        int c4 = (f4 & 127) * 4;
        float4 v = *(const float4*)(cw + (size_t)k * Cdim + c4);
        ushort4 u;
        u.x = f2bf(v.x); u.y = f2bf(v.y); u.z = f2bf(v.z); u.w = f2bf(v.w);
        *(ushort4*)&cw_s[k][c4] = u;
    }

    float4 sc4, c24;
    if (t < 256) {
        sc4 = *(const float4*)(scale + 4 * q);
        c24 = *(const float4*)(c2g + 4 * q);
    }

    const float* xb = x + (size_t)b * Cdim * Ndim;

    // prefetch chunk 0: thread covers c pairs {2crg+64i, +1}, px pair 2pp
    float2 pa[8], pb[8];
    {
        int n0 = pw * 512;
        #pragma unroll
        for (int i = 0; i < 8; ++i) {
            int c = 2 * crg + 64 * i;
            pa[i] = *(const float2*)(xb + (size_t)c * Ndim + n0 + 2 * pp);
            pb[i] = *(const float2*)(xb + (size_t)(c + 1) * Ndim + n0 + 2 * pp);
        }
    }

    f32x4 acc[2][4];                 // [k-half][c-tile] ; wave owns 64 c
    #pragma unroll
    for (int kt = 0; kt < 2; ++kt)
        #pragma unroll
        for (int ct = 0; ct < 4; ++ct) acc[kt][ct] = (f32x4){0.f, 0.f, 0.f, 0.f};
    float wsum_r[4] = {0.f, 0.f, 0.f, 0.f};   // valid for t<256

    __syncthreads();   // cw staging done

    for (int ci = 0; ci < NCH; ++ci) {
        // ---------------- stage x from prefetch regs ----------------
        float x2p0 = 0.f, x2p1 = 0.f;
        #pragma unroll
        for (int i = 0; i < 8; ++i) {
            int c = 2 * crg + 64 * i;
            float2 a = pa[i], bb = pb[i];
            unsigned short ax = f2bf(a.x), ay = f2bf(a.y);
            unsigned short bx = f2bf(bb.x), by = f2bf(bb.y);
            ushort2 u;
            u.x = ax; u.y = ay; *(ushort2*)&x_t[c][2 * pp] = u;       // [c][px]
            u.x = bx; u.y = by; *(ushort2*)&x_t[c + 1][2 * pp] = u;
            u.x = ax; u.y = bx; *(ushort2*)&x_n[2 * pp][c] = u;       // [px][c]
            u.x = ay; u.y = by; *(ushort2*)&x_n[2 * pp + 1][c] = u;
            x2p0 += a.x * a.x + bb.x * bb.x;
            x2p1 += a.y * a.y + bb.y * bb.y;
        }
        // per-wave x2 partials: collapse crg within wave (lanes xor 16,32)
        x2p0 += __shfl_xor(x2p0, 16); x2p1 += __shfl_xor(x2p1, 16);
        x2p0 += __shfl_xor(x2p0, 32); x2p1 += __shfl_xor(x2p1, 32);
        if (lane < 16) {
            float2 v; v.x = x2p0; v.y = x2p1;
            *(float2*)&x2_w[wv][2 * pp] = v;
        }
        // prefetch next chunk (overlaps pass1/softmax/pass2)
        if (ci + 1 < NCH) {
            int nn = pw * 512 + (ci + 1) * 32;
            #pragma unroll
            for (int i = 0; i < 8; ++i) {
                int c = 2 * crg + 64 * i;
                pa[i] = *(const float2*)(xb + (size_t)c * Ndim + nn + 2 * pp);
                pb[i] = *(const float2*)(xb + (size_t)(c + 1) * Ndim + nn + 2 * pp);
            }
        }
        __syncthreads();

        // ---------------- pass 1: dots via MFMA (c split across wave pairs) ----
        {
            f32x4 d = (f32x4){0.f, 0.f, 0.f, 0.f};
            #pragma unroll
            for (int s = 0; s < 8; ++s) {
                int col = 256 * ch + 32 * s + 8 * lq;
                bf16x8 av = *(const bf16x8*)&x_n[16 * pt + lr][col];
                bf16x8 bv = *(const bf16x8*)&cw_s[16 * kt2 + lr][col];
                d = __builtin_amdgcn_mfma_f32_16x16x32_bf16(av, bv, d, 0, 0, 0);
            }
            #pragma unroll
            for (int r = 0; r < 4; ++r)
                S_s[ch][16 * pt + 4 * lq + r][16 * kt2 + lr] = d[r];
        }
        __syncthreads();

        // ---------------- softmax (t<256: px = t>>3, k-quad q) ----------------
        if (t < 256) {
            float4 dv0 = *(const float4*)&S_s[0][px][4 * q];
            float4 dv1 = *(const float4*)&S_s[1][px][4 * q];
            float xx = 0.f;
            #pragma unroll
            for (int w = 0; w < 8; ++w) xx += x2_w[w][px];
            float d0 = sc4.x * (xx - 2.f * (dv0.x + dv1.x) + c24.x);
            float d1 = sc4.y * (xx - 2.f * (dv0.y + dv1.y) + c24.y);
            float d2 = sc4.z * (xx - 2.f * (dv0.z + dv1.z) + c24.z);
            float d3 = sc4.w * (xx - 2.f * (dv0.w + dv1.w) + c24.w);
            float m = fmaxf(fmaxf(d0, d1), fmaxf(d2, d3));
            m = fmaxf(m, __shfl_xor(m, 1));
            m = fmaxf(m, __shfl_xor(m, 2));
            m = fmaxf(m, __shfl_xor(m, 4));
            float e0 = __expf(d0 - m), e1 = __expf(d1 - m);
            float e2 = __expf(d2 - m), e3 = __expf(d3 - m);
            float ss = e0 + e1 + e2 + e3;
            ss += __shfl_xor(ss, 1);
            ss += __shfl_xor(ss, 2);
            ss += __shfl_xor(ss, 4);
            float inv = 1.f / ss;
            float w0 = e0 * inv, w1 = e1 * inv, w2 = e2 * inv, w3 = e3 * inv;
            wsum_r[0] += w0; wsum_r[1] += w1; wsum_r[2] += w2; wsum_r[3] += w3;
            w_t[4 * q + 0][px] = f2bf(w0);
            w_t[4 * q + 1][px] = f2bf(w1);
            w_t[4 * q + 2][px] = f2bf(w2);
            w_t[4 * q + 3][px] = f2bf(w3);
        }
        __syncthreads();

        // ---------------- pass 2: out-tile MFMA, wave owns 64 c ----------------
        {
            bf16x8 a0 = *(const bf16x8*)&w_t[lr][8 * lq];
            bf16x8 a1 = *(const bf16x8*)&w_t[16 + lr][8 * lq];
            #pragma unroll
            for (int ct = 0; ct < 4; ++ct) {
                bf16x8 bv = *(const bf16x8*)&x_t[64 * wv + 16 * ct + lr][8 * lq];
                acc[0][ct] = __builtin_amdgcn_mfma_f32_16x16x32_bf16(a0, bv, acc[0][ct], 0, 0, 0);
                acc[1][ct] = __builtin_amdgcn_mfma_f32_16x16x32_bf16(a1, bv, acc[1][ct], 0, 0, 0);
            }
        }
        __syncthreads();   // x_t/x_n/w_t reusable next chunk
    }

    // ---------------- epilogue ----------------
    // wsum: collapse px within each of waves 0..3, then cross-wave sum
    if (t < 256) {
        #pragma unroll
        for (int j = 0; j < 4; ++j) {
            float v = wsum_r[j];
            v += __shfl_xor(v, 8);
            v += __shfl_xor(v, 16);
            v += __shfl_xor(v, 32);
            if (lane < 8) wsum_w[wv][4 * lane + j] = v;
        }
    }
    {
        float* pbuf = part + (size_t)blk * (Kdim * Cdim);
        #pragma unroll
        for (int kt = 0; kt < 2; ++kt)
            #pragma unroll
            for (int ct = 0; ct < 4; ++ct)
                #pragma unroll
                for (int r = 0; r < 4; ++r)
                    pbuf[(size_t)(16 * kt + 4 * lq + r) * Cdim + 64 * wv + 16 * ct + lr] =
                        acc[kt][ct][r];
    }
    __syncthreads();
    if (t < 32) {
        float s = wsum_w[0][t] + wsum_w[1][t] + wsum_w[2][t] + wsum_w[3][t];
        wsum_part[blk * Kdim + t] = s;
    }
}

// ---------------------------------------------------------------------------
// K2: reduce 8 partials per (b,k) + subtract wsum*cw.
// ---------------------------------------------------------------------------
__global__ __launch_bounds__(256) void k2_reduce(const float* __restrict__ part,
                                                 const float* __restrict__ wsum_part,
                                                 const float* __restrict__ cw,
                                                 float* __restrict__ out) {
    int blk = blockIdx.x;
    int b = blk >> 5, k = blk & 31;
    int t = threadIdx.x;
    float ws = 0.f;
    #pragma unroll
    for (int p = 0; p < PWIN; ++p) ws += wsum_part[(b * PWIN + p) * Kdim + k];
    int c = 2 * t;
    float sx = 0.f, sy = 0.f;
    #pragma unroll
    for (int p = 0; p < PWIN; ++p) {
        const float2 v = *(const float2*)(part + ((size_t)(b * PWIN + p) * Kdim + k) * Cdim + c);
        sx += v.x;
        sy += v.y;
    }
    float2 cv = *(const float2*)(cw + (size_t)k * Cdim + c);
    float2 o;
    o.x = sx - ws * cv.x;
    o.y = sy - ws * cv.y;
    *(float2*)(out + ((size_t)b * Kdim + k) * Cdim + c) = o;
}

// ---------------------------------------------------------------------------
extern "C" void kernel_launch(void* const* d_in, const int* in_sizes, int n_in,
                              void* d_out, int out_size, void* d_ws, size_t ws_size,
                              hipStream_t stream) {
    const float* x     = (const float*)d_in[0];   // [B][C][N]
    const float* cw    = (const float*)d_in[1];   // [K][C]
    const float* scale = (const float*)d_in[2];   // [K]
    float* out = (float*)d_out;                   // [B][K][C]

    char* wsb = (char*)d_ws;
    float* part      = (float*)wsb;
    float* wsum_part = (float*)(wsb + WS_WSUM_OFF);
    float* c2        = (float*)(wsb + WS_C2_OFF);

    k0_c2<<<1, 256, 0, stream>>>(cw, c2);
    k1_fused<<<Bdim * PWIN, 512, 0, stream>>>(x, cw, scale, c2, part, wsum_part);
    k2_reduce<<<Bdim * Kdim, 256, 0, stream>>>(part, wsum_part, cw, out);
}